// Round 1
// baseline (808.871 us; speedup 1.0000x reference)
//
#include <hip/hip_runtime.h>
#include <hip/hip_bf16.h>

// PMA pooling block:
//  scores[n,h] = h[n]·c[h] + d[h]        (c,d precomputed from seed,Wq,Wk)
//  T[g,h*256+d] = segment softmax-weighted mean of h rows (unstabilized exp:
//                 |score| <~ 3 for this data, ratios identical to reference)
//  o  = Tb @ P2b^T + const   (P2 = out_w ∘ Wv folded, bf16 [256,1024], MFMA)
//  x1 = LN(o+seed); u = relu(x1@w1^T+b1); f = u@w2^T+b2; out = LN(x1+f)·mask
//  -> o/u/f + both LNs fused into ONE kernel (LDS-resident intermediates)

#define DIM 256
#define CHUNK 32

typedef short bf16x8 __attribute__((ext_vector_type(8)));  // 8 bf16 = 4 VGPRs
typedef float f32x4  __attribute__((ext_vector_type(4)));
#define MFMA16(a, b, c) __builtin_amdgcn_mfma_f32_16x16x32_bf16(a, b, c, 0, 0, 0)

// ---- workspace layout (float offsets; all bf16 arrays 16B-aligned) ----
#define OFF_C      0          // c[4][256] fp32
#define OFF_D      1024       // dconst[4]
#define OFF_CONST  1040       // constvec[256]
#define OFF_P2B    2048       // P2 bf16 [256][1024]
#define OFF_W1B    133120     // w1 bf16 [1024][256]
#define OFF_W2B    264192     // w2 bf16 [256][1024]
#define OFF_TB     395264     // T  bf16 [4096][1024]
#define OFF_CNT    6162432    // cnt int [4096]

// ================= prep: c/dconst/constvec + P2b + w1b/w2b ==============
// blocks 0..1023: P2b; block 1024: prep1; 1025..1152: w1b; 1153..1280: w2b
__global__ __launch_bounds__(256) void prep_all_kernel(
    const float* __restrict__ seed, const float* __restrict__ ipw,
    const float* __restrict__ ipb, const float* __restrict__ out_w,
    const float* __restrict__ out_b, const float* __restrict__ w1,
    const float* __restrict__ w2,
    float* __restrict__ cvec, float* __restrict__ dconst,
    float* __restrict__ constvec, __hip_bfloat16* __restrict__ P2b,
    __hip_bfloat16* __restrict__ w1b, __hip_bfloat16* __restrict__ w2b)
{
    int b = blockIdx.x, t = threadIdx.x;
    __shared__ float q_s[DIM];
    if (b < 1024) {
        // P2[i][hD*256+t] = sum_j out_w[i,hD*64+j]*Wv[hD*64+j][t]
        int i = b >> 2, hD = b & 3;
        float a = 0.f;
        for (int j = 0; j < 64; ++j)
            a += out_w[i * DIM + hD * 64 + j]
               * ipw[(size_t)(2 * DIM + hD * 64 + j) * DIM + t];
        P2b[(size_t)i * 1024 + hD * DIM + t] = __float2bfloat16(a);
    } else if (b == 1024) {
        const float scale = 0.125f; // 1/sqrt(64)
        float acc = ipb[t];
        for (int d = 0; d < DIM; ++d) acc += seed[d] * ipw[t * DIM + d];
        q_s[t] = acc;
        __syncthreads();
        for (int hh = 0; hh < 4; ++hh) {
            float a = 0.f;
            for (int j = 0; j < 64; ++j)
                a += q_s[hh * 64 + j] * ipw[(size_t)(DIM + hh * 64 + j) * DIM + t];
            cvec[hh * DIM + t] = a * scale;
        }
        if (t < 4) {
            float a = 0.f;
            for (int j = 0; j < 64; ++j)
                a += q_s[t * 64 + j] * ipb[DIM + t * 64 + j];
            dconst[t] = a * scale;
        }
        float cc = out_b[t];
        for (int c = 0; c < DIM; ++c)
            cc += out_w[t * DIM + c] * ipb[2 * DIM + c];
        constvec[t] = cc;
    } else if (b < 1153) {
        int base = (b - 1025) * 2048 + t;
        for (int i = 0; i < 8; ++i)
            w1b[base + i * 256] = __float2bfloat16(w1[base + i * 256]);
    } else {
        int base = (b - 1153) * 2048 + t;
        for (int i = 0; i < 8; ++i)
            w2b[base + i * 256] = __float2bfloat16(w2[base + i * 256]);
    }
}

// ================= attn pooling: per-graph exp-weighted mean ============
// Software-pipelined: chunk c+1 is prefetched into registers while the
// score/weighted-sum phases of chunk c run (HBM latency hidden under VALU).
__global__ __launch_bounds__(256) void attn_pool_kernel(
    const float* __restrict__ hmat, const int* __restrict__ batch,
    const float* __restrict__ cvec, const float* __restrict__ dconst,
    __hip_bfloat16* __restrict__ Tb, int* __restrict__ cnt, int N)
{
    int g = blockIdx.x;
    int tid = threadIdx.x;
    int lane = tid & 63, wave = tid >> 6;

    __shared__ float hbuf[CHUNK][DIM];   // 32 KB
    __shared__ float4 esc[CHUNK];        // e per node, 4 heads
    __shared__ float lred[4][4];         // [wave][head] partial denominators

    int s, e;
    { int l = 0, r = N;
      while (l < r) { int m = (l + r) >> 1; if (batch[m] < g) l = m + 1; else r = m; }
      s = l; }
    { int l = s, r = N;
      while (l < r) { int m = (l + r) >> 1; if (batch[m] < g + 1) l = m + 1; else r = m; }
      e = l; }

    if (tid == 0) cnt[g] = e - s;
    size_t tbase = (size_t)g * 1024;
    if (e == s) {
        __hip_bfloat16 z = __float2bfloat16(0.f);
        Tb[tbase + tid] = z; Tb[tbase + 256 + tid] = z;
        Tb[tbase + 512 + tid] = z; Tb[tbase + 768 + tid] = z;
        return;
    }

    int hh = lane & 3, seg = lane >> 2;
    const float* cb = cvec + hh * DIM + seg * 16;
    float4 cr0 = *(const float4*)(cb + 0);
    float4 cr1 = *(const float4*)(cb + 4);
    float4 cr2 = *(const float4*)(cb + 8);
    float4 cr3 = *(const float4*)(cb + 12);
    float dc_mine = dconst[hh];

    float S0 = 0.f, S1 = 0.f, S2 = 0.f, S3 = 0.f;
    float lp = 0.f;  // meaningful on lanes 0..3 only (head = lane)

    // ---- prologue: prefetch chunk 0 into registers ----
    float4 rbuf[8];
    {
        int cc0 = min(CHUNK, e - s);
#pragma unroll
        for (int i = 0; i < 8; ++i) {
            int idx = tid + i * 256;
            if (idx < cc0 * 64) {
                int j = idx >> 6, q4 = idx & 63;
                rbuf[i] = *(const float4*)&hmat[(size_t)(s + j) * DIM + q4 * 4];
            }
        }
    }

    for (int n0 = s; n0 < e; n0 += CHUNK) {
        int ccnt = min(CHUNK, e - n0);
        // write prefetched registers -> LDS
#pragma unroll
        for (int i = 0; i < 8; ++i) {
            int idx = tid + i * 256;
            if (idx < ccnt * 64) {
                int j = idx >> 6, q4 = idx & 63;
                *(float4*)&hbuf[j][q4 * 4] = rbuf[i];
            }
        }
        __syncthreads();

        // issue next chunk's global loads (retire under the compute below)
        int n1 = n0 + CHUNK;
        if (n1 < e) {
            int cn = min(CHUNK, e - n1);
#pragma unroll
            for (int i = 0; i < 8; ++i) {
                int idx = tid + i * 256;
                if (idx < cn * 64) {
                    int j = idx >> 6, q4 = idx & 63;
                    rbuf[i] = *(const float4*)&hmat[(size_t)(n1 + j) * DIM + q4 * 4];
                }
            }
        }

        // scores + exp
        for (int j = wave; j < ccnt; j += 4) {
            const float* hb = &hbuf[j][seg * 16];
            float4 h0 = *(const float4*)(hb + 0);
            float4 h1 = *(const float4*)(hb + 4);
            float4 h2 = *(const float4*)(hb + 8);
            float4 h3 = *(const float4*)(hb + 12);
            float p = h0.x * cr0.x + h0.y * cr0.y + h0.z * cr0.z + h0.w * cr0.w
                    + h1.x * cr1.x + h1.y * cr1.y + h1.z * cr1.z + h1.w * cr1.w
                    + h2.x * cr2.x + h2.y * cr2.y + h2.z * cr2.z + h2.w * cr2.w
                    + h3.x * cr3.x + h3.y * cr3.y + h3.z * cr3.z + h3.w * cr3.w;
            p += __shfl_xor(p, 4);
            p += __shfl_xor(p, 8);
            p += __shfl_xor(p, 16);
            p += __shfl_xor(p, 32);
            if (lane < 4) {
                float ev = __expf(p + dc_mine);   // |score| small: safe unstabilized
                ((float*)&esc[j])[lane] = ev;
                lp += ev;
            }
        }
        __syncthreads();

        // weighted sum
        for (int j = 0; j < ccnt; ++j) {
            float4 e4 = esc[j];                   // LDS broadcast
            float hv = hbuf[j][tid];
            S0 = fmaf(e4.x, hv, S0); S1 = fmaf(e4.y, hv, S1);
            S2 = fmaf(e4.z, hv, S2); S3 = fmaf(e4.w, hv, S3);
        }
        __syncthreads();
    }

    if (lane < 4) lred[wave][lane] = lp;
    __syncthreads();
    float l0 = lred[0][0] + lred[1][0] + lred[2][0] + lred[3][0];
    float l1 = lred[0][1] + lred[1][1] + lred[2][1] + lred[3][1];
    float l2 = lred[0][2] + lred[1][2] + lred[2][2] + lred[3][2];
    float l3 = lred[0][3] + lred[1][3] + lred[2][3] + lred[3][3];
    Tb[tbase + tid]       = __float2bfloat16(S0 / l0);
    Tb[tbase + 256 + tid] = __float2bfloat16(S1 / l1);
    Tb[tbase + 512 + tid] = __float2bfloat16(S2 / l2);
    Tb[tbase + 768 + tid] = __float2bfloat16(S3 / l3);
}

// === fused: o = Tb@P2b^T+const; x1 = LN1(o+seed); u = relu(x1@w1^T+b1);
//            f = u@w2^T+b2; out = LN2(x1+f)*mask — all intermediates in LDS.
// 256 threads = 4 waves; each wave owns a 64-col (o/f) or 256-col (u) slice.
// LDS strides padded (+4 f32 / +8 bf16) so row-major reads hit rotated banks.
__global__ __launch_bounds__(256) void mlp_fused_kernel(
    const __hip_bfloat16* __restrict__ Tb, const __hip_bfloat16* __restrict__ P2b,
    const float* __restrict__ constvec, const float* __restrict__ seed,
    const float* __restrict__ g1, const float* __restrict__ be1,
    const __hip_bfloat16* __restrict__ w1b, const float* __restrict__ b1,
    const __hip_bfloat16* __restrict__ w2b, const float* __restrict__ b2,
    const float* __restrict__ g2, const float* __restrict__ be2,
    const int* __restrict__ cnt, float* __restrict__ outp)
{
    int m0 = blockIdx.x * 16;
    int tid = threadIdx.x;
    int w = tid >> 6, lane = tid & 63, quad = lane >> 4, l16 = lane & 15;

    __shared__ float x1s[16][260];               // 16.6 KB  (x1 fp32, residual)
    __shared__ __hip_bfloat16 x1bs[16][264];     //  8.25 KB (x1 bf16, GEMM A)
    __shared__ __hip_bfloat16 us[16][1032];      // 33 KB    (u bf16, GEMM A)
    __shared__ float redS[4][16], redQ[4][16];   // cross-wave LN partials

    // ---------- phase 0: o-GEMM (K=1024), cols [w*64, w*64+64) ----------
    f32x4 acc0[4];
#pragma unroll
    for (int i = 0; i < 4; ++i) acc0[i] = (f32x4){0.f, 0.f, 0.f, 0.f};
    const __hip_bfloat16* Ap0 = Tb + (size_t)(m0 + l16) * 1024 + quad * 8;
    const __hip_bfloat16* Bp0 = P2b + (size_t)(w * 64 + l16) * 1024 + quad * 8;
    for (int k0 = 0; k0 < 1024; k0 += 32) {
        bf16x8 a = *(const bf16x8*)(Ap0 + k0);
#pragma unroll
        for (int nt = 0; nt < 4; ++nt) {
            bf16x8 b = *(const bf16x8*)(Bp0 + (size_t)nt * 16 * 1024 + k0);
            acc0[nt] = MFMA16(a, b, acc0[nt]);
        }
    }
    // epilogue: +const+seed, LN1 partials (this wave covers 64 of 256 cols)
    float v0[4][4];
    {
        float sum[4] = {0, 0, 0, 0}, sq[4] = {0, 0, 0, 0};
#pragma unroll
        for (int nt = 0; nt < 4; ++nt) {
            int col = w * 64 + nt * 16 + l16;
            float cv = constvec[col] + seed[col];
#pragma unroll
            for (int r = 0; r < 4; ++r) {
                float x = acc0[nt][r] + cv;
                v0[nt][r] = x; sum[r] += x; sq[r] += x * x;
            }
        }
#pragma unroll
        for (int r = 0; r < 4; ++r) {
            float s_ = sum[r], q_ = sq[r];
            s_ += __shfl_xor(s_, 1);  q_ += __shfl_xor(q_, 1);
            s_ += __shfl_xor(s_, 2);  q_ += __shfl_xor(q_, 2);
            s_ += __shfl_xor(s_, 4);  q_ += __shfl_xor(q_, 4);
            s_ += __shfl_xor(s_, 8);  q_ += __shfl_xor(q_, 8);
            if (l16 == 0) { redS[w][quad * 4 + r] = s_; redQ[w][quad * 4 + r] = q_; }
        }
    }
    __syncthreads();
    {
        float mu_r[4], rs_r[4];
#pragma unroll
        for (int r = 0; r < 4; ++r) {
            int row = quad * 4 + r;
            float s_ = redS[0][row] + redS[1][row] + redS[2][row] + redS[3][row];
            float q_ = redQ[0][row] + redQ[1][row] + redQ[2][row] + redQ[3][row];
            float mu = s_ * (1.f / 256);
            float var = q_ * (1.f / 256) - mu * mu;
            mu_r[r] = mu;
            rs_r[r] = rsqrtf(fmaxf(var, 0.f) + 1e-5f);
        }
#pragma unroll
        for (int nt = 0; nt < 4; ++nt) {
            int col = w * 64 + nt * 16 + l16;
            float gg = g1[col], bb = be1[col];
#pragma unroll
            for (int r = 0; r < 4; ++r) {
                int row = quad * 4 + r;
                float y = (v0[nt][r] - mu_r[r]) * rs_r[r] * gg + bb;
                x1s[row][col] = y;
                x1bs[row][col] = __float2bfloat16(y);
            }
        }
    }
    __syncthreads();

    // ---------- phase 1: u-GEMM (K=256), cols [w*256, w*256+256) ----------
    f32x4 acc1[16];
#pragma unroll
    for (int i = 0; i < 16; ++i) acc1[i] = (f32x4){0.f, 0.f, 0.f, 0.f};
    const __hip_bfloat16* Bp1 = w1b + (size_t)(w * 256 + l16) * 256 + quad * 8;
#pragma unroll
    for (int k0 = 0; k0 < 256; k0 += 32) {
        bf16x8 a = *(const bf16x8*)&x1bs[l16][quad * 8 + k0];
#pragma unroll
        for (int nt = 0; nt < 16; ++nt) {
            bf16x8 b = *(const bf16x8*)(Bp1 + (size_t)nt * 16 * 256 + k0);
            acc1[nt] = MFMA16(a, b, acc1[nt]);
        }
    }
#pragma unroll
    for (int nt = 0; nt < 16; ++nt) {
        int col = w * 256 + nt * 16 + l16;
        float bb = b1[col];
#pragma unroll
        for (int r = 0; r < 4; ++r) {
            int row = quad * 4 + r;
            us[row][col] = __float2bfloat16(fmaxf(acc1[nt][r] + bb, 0.f));
        }
    }
    __syncthreads();

    // ---------- phase 2: f-GEMM (K=1024) + residual + LN2 + mask ----------
    f32x4 acc2[4];
#pragma unroll
    for (int i = 0; i < 4; ++i) acc2[i] = (f32x4){0.f, 0.f, 0.f, 0.f};
    const __hip_bfloat16* Bp2 = w2b + (size_t)(w * 64 + l16) * 1024 + quad * 8;
    for (int k0 = 0; k0 < 1024; k0 += 32) {
        bf16x8 a = *(const bf16x8*)&us[l16][quad * 8 + k0];
#pragma unroll
        for (int nt = 0; nt < 4; ++nt) {
            bf16x8 b = *(const bf16x8*)(Bp2 + (size_t)nt * 16 * 1024 + k0);
            acc2[nt] = MFMA16(a, b, acc2[nt]);
        }
    }
    float v2[4][4];
    {
        float sum[4] = {0, 0, 0, 0}, sq[4] = {0, 0, 0, 0};
#pragma unroll
        for (int nt = 0; nt < 4; ++nt) {
            int col = w * 64 + nt * 16 + l16;
            float bb = b2[col];
#pragma unroll
            for (int r = 0; r < 4; ++r) {
                int row = quad * 4 + r;
                float x = acc2[nt][r] + bb + x1s[row][col];
                v2[nt][r] = x; sum[r] += x; sq[r] += x * x;
            }
        }
#pragma unroll
        for (int r = 0; r < 4; ++r) {
            float s_ = sum[r], q_ = sq[r];
            s_ += __shfl_xor(s_, 1);  q_ += __shfl_xor(q_, 1);
            s_ += __shfl_xor(s_, 2);  q_ += __shfl_xor(q_, 2);
            s_ += __shfl_xor(s_, 4);  q_ += __shfl_xor(q_, 4);
            s_ += __shfl_xor(s_, 8);  q_ += __shfl_xor(q_, 8);
            if (l16 == 0) { redS[w][quad * 4 + r] = s_; redQ[w][quad * 4 + r] = q_; }
        }
    }
    __syncthreads();
    {
#pragma unroll
        for (int r = 0; r < 4; ++r) {
            int row = quad * 4 + r;
            float s_ = redS[0][row] + redS[1][row] + redS[2][row] + redS[3][row];
            float q_ = redQ[0][row] + redQ[1][row] + redQ[2][row] + redQ[3][row];
            float mu = s_ * (1.f / 256);
            float var = q_ * (1.f / 256) - mu * mu;
            float rs = rsqrtf(fmaxf(var, 0.f) + 1e-5f);
            int gr = m0 + row;
            float mask = (cnt[gr] > 0) ? 1.f : 0.f;
#pragma unroll
            for (int nt = 0; nt < 4; ++nt) {
                int col = w * 64 + nt * 16 + l16;
                float y = ((v2[nt][r] - mu) * rs * g2[col] + be2[col]) * mask;
                outp[(size_t)gr * 256 + col] = y;
            }
        }
    }
}

extern "C" void kernel_launch(void* const* d_in, const int* in_sizes, int n_in,
                              void* d_out, int out_size, void* d_ws, size_t ws_size,
                              hipStream_t stream) {
    const float* h     = (const float*)d_in[0];
    const int*   batch = (const int*)d_in[1];
    const float* seed  = (const float*)d_in[3];
    const float* ipw   = (const float*)d_in[4];
    const float* ipb   = (const float*)d_in[5];
    const float* out_w = (const float*)d_in[6];
    const float* out_b = (const float*)d_in[7];
    const float* w1    = (const float*)d_in[8];
    const float* b1    = (const float*)d_in[9];
    const float* w2    = (const float*)d_in[10];
    const float* b2    = (const float*)d_in[11];
    const float* g1    = (const float*)d_in[12];
    const float* be1   = (const float*)d_in[13];
    const float* g2    = (const float*)d_in[14];
    const float* be2   = (const float*)d_in[15];

    int N = in_sizes[1];            // 400000 nodes
    int G = out_size / DIM;         // 4096 graphs

    float* ws = (float*)d_ws;
    float* cvec     = ws + OFF_C;
    float* dconst   = ws + OFF_D;
    float* constvec = ws + OFF_CONST;
    __hip_bfloat16* P2b = (__hip_bfloat16*)(ws + OFF_P2B);
    __hip_bfloat16* w1b = (__hip_bfloat16*)(ws + OFF_W1B);
    __hip_bfloat16* w2b = (__hip_bfloat16*)(ws + OFF_W2B);
    __hip_bfloat16* Tb  = (__hip_bfloat16*)(ws + OFF_TB);
    int*   cnt      = (int*)(ws + OFF_CNT);

    prep_all_kernel<<<1281, 256, 0, stream>>>(seed, ipw, ipb, out_w, out_b, w1, w2,
                                              cvec, dconst, constvec, P2b, w1b, w2b);
    attn_pool_kernel<<<G, 256, 0, stream>>>(h, batch, cvec, dconst, Tb, cnt, N);
    mlp_fused_kernel<<<G / 16, 256, 0, stream>>>(Tb, P2b, constvec, seed, g1, be1,
                                                 w1b, b1, w2b, b2, g2, be2, cnt,
                                                 (float*)d_out);
}

// Round 2
// 675.051 us; speedup vs baseline: 1.1982x; 1.1982x over previous
//
#include <hip/hip_runtime.h>
#include <hip/hip_bf16.h>

// PMA pooling block:
//  scores[n,h] = h[n]·c[h] + d[h]        (c,d precomputed from seed,Wq,Wk)
//  T[g,h*256+d] = segment softmax-weighted mean of h rows (unstabilized exp:
//                 |score| <~ 3 for this data, ratios identical to reference)
//  o  = Tb @ P2b^T + const   (P2 = out_w ∘ Wv folded, bf16 [256,1024], MFMA)
//  x1 = LN(o+seed); u = relu(x1@w1^T+b1); f = u@w2^T+b2; out = LN(x1+f)·mask
//  -> o/u/f + both LNs fused into ONE kernel (LDS-resident intermediates)
// attn_pool: double-buffered global_load_lds staging (async, no VGPR round
// trip — round-1's register prefetch spilled to scratch: 407MB writeback),
// per-graph ranges via precomputed starts[] (kills 38-step binary search).

#define DIM 256
#define CHUNK 32

typedef short bf16x8 __attribute__((ext_vector_type(8)));  // 8 bf16 = 4 VGPRs
typedef float f32x4  __attribute__((ext_vector_type(4)));
#define MFMA16(a, b, c) __builtin_amdgcn_mfma_f32_16x16x32_bf16(a, b, c, 0, 0, 0)

// async global->LDS, 16B per lane; LDS dest = wave-uniform base + lane*16
#define GLOAD_LDS16(gp, lp)                                          \
    __builtin_amdgcn_global_load_lds(                                \
        (const __attribute__((address_space(1))) void*)(gp),         \
        (__attribute__((address_space(3))) void*)(lp), 16, 0, 0)

// ---- workspace layout (float offsets; all bf16 arrays 16B-aligned) ----
#define OFF_C      0          // c[4][256] fp32
#define OFF_D      1024       // dconst[4]
#define OFF_CONST  1040       // constvec[256]
#define OFF_P2B    2048       // P2 bf16 [256][1024]
#define OFF_W1B    133120     // w1 bf16 [1024][256]
#define OFF_W2B    264192     // w2 bf16 [256][1024]
#define OFF_TB     395264     // T  bf16 [4096][1024]
#define OFF_CNT    6162432    // cnt int [4096]
#define OFF_STARTS 6166528    // starts int [4097]

// ================= prep: c/dconst/constvec + P2b + w1b/w2b + starts =====
// blocks 0..1023: P2b; 1024: prep1; 1025..1152: w1b; 1153..1280: w2b;
// 1281+: segment starts scatter (sorted batch -> unique writer per graph)
__global__ __launch_bounds__(256) void prep_all_kernel(
    const float* __restrict__ seed, const float* __restrict__ ipw,
    const float* __restrict__ ipb, const float* __restrict__ out_w,
    const float* __restrict__ out_b, const float* __restrict__ w1,
    const float* __restrict__ w2, const int* __restrict__ batch,
    float* __restrict__ cvec, float* __restrict__ dconst,
    float* __restrict__ constvec, __hip_bfloat16* __restrict__ P2b,
    __hip_bfloat16* __restrict__ w1b, __hip_bfloat16* __restrict__ w2b,
    int* __restrict__ starts, int N, int G)
{
    int b = blockIdx.x, t = threadIdx.x;
    __shared__ float q_s[DIM];
    if (b < 1024) {
        // P2[i][hD*256+t] = sum_j out_w[i,hD*64+j]*Wv[hD*64+j][t]
        int i = b >> 2, hD = b & 3;
        float a = 0.f;
        for (int j = 0; j < 64; ++j)
            a += out_w[i * DIM + hD * 64 + j]
               * ipw[(size_t)(2 * DIM + hD * 64 + j) * DIM + t];
        P2b[(size_t)i * 1024 + hD * DIM + t] = __float2bfloat16(a);
    } else if (b == 1024) {
        const float scale = 0.125f; // 1/sqrt(64)
        float acc = ipb[t];
        for (int d = 0; d < DIM; ++d) acc += seed[d] * ipw[t * DIM + d];
        q_s[t] = acc;
        __syncthreads();
        for (int hh = 0; hh < 4; ++hh) {
            float a = 0.f;
            for (int j = 0; j < 64; ++j)
                a += q_s[hh * 64 + j] * ipw[(size_t)(DIM + hh * 64 + j) * DIM + t];
            cvec[hh * DIM + t] = a * scale;
        }
        if (t < 4) {
            float a = 0.f;
            for (int j = 0; j < 64; ++j)
                a += q_s[t * 64 + j] * ipb[DIM + t * 64 + j];
            dconst[t] = a * scale;
        }
        float cc = out_b[t];
        for (int c = 0; c < DIM; ++c)
            cc += out_w[t * DIM + c] * ipb[2 * DIM + c];
        constvec[t] = cc;
    } else if (b < 1153) {
        int base = (b - 1025) * 2048 + t;
        for (int i = 0; i < 8; ++i)
            w1b[base + i * 256] = __float2bfloat16(w1[base + i * 256]);
    } else if (b < 1281) {
        int base = (b - 1153) * 2048 + t;
        for (int i = 0; i < 8; ++i)
            w2b[base + i * 256] = __float2bfloat16(w2[base + i * 256]);
    } else {
        int n = (b - 1281) * 256 + t;
        if (n < N) {
            int bn = batch[n];
            int bp = (n == 0) ? -1 : batch[n - 1];
            for (int gg = bp + 1; gg <= bn; ++gg) starts[gg] = n;
            if (n == N - 1)
                for (int gg = bn + 1; gg <= G; ++gg) starts[gg] = N;
        }
    }
}

// ================= attn pooling: per-graph exp-weighted mean ============
// Double-buffered async staging: chunk c+1 streams into buf^1 via
// global_load_lds while scores of chunk c run; __syncthreads' implicit
// vmcnt(0) drain is the completion wait.
__global__ __launch_bounds__(256) void attn_pool_kernel(
    const float* __restrict__ hmat, const int* __restrict__ starts,
    const float* __restrict__ cvec, const float* __restrict__ dconst,
    __hip_bfloat16* __restrict__ Tb, int* __restrict__ cnt)
{
    int g = blockIdx.x;
    int tid = threadIdx.x;
    int lane = tid & 63, wave = tid >> 6;

    __shared__ float hbuf[2][CHUNK][DIM];  // 64 KB, linear (gload_lds dest)
    __shared__ float4 esc[CHUNK];          // e per node, 4 heads
    __shared__ float lred[4][4];           // [wave][head] partial denominators

    int s = starts[g], e = starts[g + 1];
    if (tid == 0) cnt[g] = e - s;
    size_t tbase = (size_t)g * 1024;
    if (e == s) {
        __hip_bfloat16 z = __float2bfloat16(0.f);
        Tb[tbase + tid] = z; Tb[tbase + 256 + tid] = z;
        Tb[tbase + 512 + tid] = z; Tb[tbase + 768 + tid] = z;
        return;
    }

    int hh = lane & 3, seg = lane >> 2;
    const float* cb = cvec + hh * DIM + seg * 16;
    float4 cr0 = *(const float4*)(cb + 0);
    float4 cr1 = *(const float4*)(cb + 4);
    float4 cr2 = *(const float4*)(cb + 8);
    float4 cr3 = *(const float4*)(cb + 12);
    float dc_mine = dconst[hh];

    float S0 = 0.f, S1 = 0.f, S2 = 0.f, S3 = 0.f;
    float lp = 0.f;  // meaningful on lanes 0..3 only (head = lane)

    // stage chunk 0 into buf 0 (8 rows per wave, 1 KB per call)
    {
        int c0 = min(CHUNK, e - s);
#pragma unroll
        for (int i = 0; i < 8; ++i) {
            int r = wave * 8 + i;
            if (r < c0)
                GLOAD_LDS16(&hmat[(size_t)(s + r) * DIM + lane * 4],
                            &hbuf[0][r][0]);
        }
    }

    int cur = 0;
    for (int n0 = s; n0 < e; n0 += CHUNK, cur ^= 1) {
        int ccnt = min(CHUNK, e - n0);
        __syncthreads();   // vmcnt(0) drain: buf[cur] staged; buf[cur^1] free

        int n1 = n0 + CHUNK;
        if (n1 < e) {      // issue next chunk; retires under scores below
            int cn = min(CHUNK, e - n1);
#pragma unroll
            for (int i = 0; i < 8; ++i) {
                int r = wave * 8 + i;
                if (r < cn)
                    GLOAD_LDS16(&hmat[(size_t)(n1 + r) * DIM + lane * 4],
                                &hbuf[cur ^ 1][r][0]);
            }
        }

        // scores + exp
        for (int j = wave; j < ccnt; j += 4) {
            const float* hb = &hbuf[cur][j][seg * 16];
            float4 h0 = *(const float4*)(hb + 0);
            float4 h1 = *(const float4*)(hb + 4);
            float4 h2 = *(const float4*)(hb + 8);
            float4 h3 = *(const float4*)(hb + 12);
            float p = h0.x * cr0.x + h0.y * cr0.y + h0.z * cr0.z + h0.w * cr0.w
                    + h1.x * cr1.x + h1.y * cr1.y + h1.z * cr1.z + h1.w * cr1.w
                    + h2.x * cr2.x + h2.y * cr2.y + h2.z * cr2.z + h2.w * cr2.w
                    + h3.x * cr3.x + h3.y * cr3.y + h3.z * cr3.z + h3.w * cr3.w;
            p += __shfl_xor(p, 4);
            p += __shfl_xor(p, 8);
            p += __shfl_xor(p, 16);
            p += __shfl_xor(p, 32);
            if (lane < 4) {
                float ev = __expf(p + dc_mine);   // |score| small: safe unstabilized
                ((float*)&esc[j])[lane] = ev;
                lp += ev;
            }
        }
        __syncthreads();   // esc ready (also lands the prefetch, post-scores)

        // weighted sum
        for (int j = 0; j < ccnt; ++j) {
            float4 e4 = esc[j];                   // LDS broadcast
            float hv = hbuf[cur][j][tid];
            S0 = fmaf(e4.x, hv, S0); S1 = fmaf(e4.y, hv, S1);
            S2 = fmaf(e4.z, hv, S2); S3 = fmaf(e4.w, hv, S3);
        }
    }

    __syncthreads();
    if (lane < 4) lred[wave][lane] = lp;
    __syncthreads();
    float l0 = lred[0][0] + lred[1][0] + lred[2][0] + lred[3][0];
    float l1 = lred[0][1] + lred[1][1] + lred[2][1] + lred[3][1];
    float l2 = lred[0][2] + lred[1][2] + lred[2][2] + lred[3][2];
    float l3 = lred[0][3] + lred[1][3] + lred[2][3] + lred[3][3];
    Tb[tbase + tid]       = __float2bfloat16(S0 / l0);
    Tb[tbase + 256 + tid] = __float2bfloat16(S1 / l1);
    Tb[tbase + 512 + tid] = __float2bfloat16(S2 / l2);
    Tb[tbase + 768 + tid] = __float2bfloat16(S3 / l3);
}

// === fused: o = Tb@P2b^T+const; x1 = LN1(o+seed); u = relu(x1@w1^T+b1);
//            f = u@w2^T+b2; out = LN2(x1+f)*mask — all intermediates in LDS.
// 256 threads = 4 waves; each wave owns a 64-col (o/f) or 256-col (u) slice.
__global__ __launch_bounds__(256) void mlp_fused_kernel(
    const __hip_bfloat16* __restrict__ Tb, const __hip_bfloat16* __restrict__ P2b,
    const float* __restrict__ constvec, const float* __restrict__ seed,
    const float* __restrict__ g1, const float* __restrict__ be1,
    const __hip_bfloat16* __restrict__ w1b, const float* __restrict__ b1,
    const __hip_bfloat16* __restrict__ w2b, const float* __restrict__ b2,
    const float* __restrict__ g2, const float* __restrict__ be2,
    const int* __restrict__ cnt, float* __restrict__ outp)
{
    int m0 = blockIdx.x * 16;
    int tid = threadIdx.x;
    int w = tid >> 6, lane = tid & 63, quad = lane >> 4, l16 = lane & 15;

    __shared__ float x1s[16][260];               // 16.6 KB  (x1 fp32, residual)
    __shared__ __hip_bfloat16 x1bs[16][264];     //  8.25 KB (x1 bf16, GEMM A)
    __shared__ __hip_bfloat16 us[16][1032];      // 33 KB    (u bf16, GEMM A)
    __shared__ float redS[4][16], redQ[4][16];   // cross-wave LN partials

    // ---------- phase 0: o-GEMM (K=1024), cols [w*64, w*64+64) ----------
    f32x4 acc0[4];
#pragma unroll
    for (int i = 0; i < 4; ++i) acc0[i] = (f32x4){0.f, 0.f, 0.f, 0.f};
    const __hip_bfloat16* Ap0 = Tb + (size_t)(m0 + l16) * 1024 + quad * 8;
    const __hip_bfloat16* Bp0 = P2b + (size_t)(w * 64 + l16) * 1024 + quad * 8;
    for (int k0 = 0; k0 < 1024; k0 += 32) {
        bf16x8 a = *(const bf16x8*)(Ap0 + k0);
#pragma unroll
        for (int nt = 0; nt < 4; ++nt) {
            bf16x8 b = *(const bf16x8*)(Bp0 + (size_t)nt * 16 * 1024 + k0);
            acc0[nt] = MFMA16(a, b, acc0[nt]);
        }
    }
    // epilogue: +const+seed, LN1 partials (this wave covers 64 of 256 cols)
    float v0[4][4];
    {
        float sum[4] = {0, 0, 0, 0}, sq[4] = {0, 0, 0, 0};
#pragma unroll
        for (int nt = 0; nt < 4; ++nt) {
            int col = w * 64 + nt * 16 + l16;
            float cv = constvec[col] + seed[col];
#pragma unroll
            for (int r = 0; r < 4; ++r) {
                float x = acc0[nt][r] + cv;
                v0[nt][r] = x; sum[r] += x; sq[r] += x * x;
            }
        }
#pragma unroll
        for (int r = 0; r < 4; ++r) {
            float s_ = sum[r], q_ = sq[r];
            s_ += __shfl_xor(s_, 1);  q_ += __shfl_xor(q_, 1);
            s_ += __shfl_xor(s_, 2);  q_ += __shfl_xor(q_, 2);
            s_ += __shfl_xor(s_, 4);  q_ += __shfl_xor(q_, 4);
            s_ += __shfl_xor(s_, 8);  q_ += __shfl_xor(q_, 8);
            if (l16 == 0) { redS[w][quad * 4 + r] = s_; redQ[w][quad * 4 + r] = q_; }
        }
    }
    __syncthreads();
    {
        float mu_r[4], rs_r[4];
#pragma unroll
        for (int r = 0; r < 4; ++r) {
            int row = quad * 4 + r;
            float s_ = redS[0][row] + redS[1][row] + redS[2][row] + redS[3][row];
            float q_ = redQ[0][row] + redQ[1][row] + redQ[2][row] + redQ[3][row];
            float mu = s_ * (1.f / 256);
            float var = q_ * (1.f / 256) - mu * mu;
            mu_r[r] = mu;
            rs_r[r] = rsqrtf(fmaxf(var, 0.f) + 1e-5f);
        }
#pragma unroll
        for (int nt = 0; nt < 4; ++nt) {
            int col = w * 64 + nt * 16 + l16;
            float gg = g1[col], bb = be1[col];
#pragma unroll
            for (int r = 0; r < 4; ++r) {
                int row = quad * 4 + r;
                float y = (v0[nt][r] - mu_r[r]) * rs_r[r] * gg + bb;
                x1s[row][col] = y;
                x1bs[row][col] = __float2bfloat16(y);
            }
        }
    }
    __syncthreads();

    // ---------- phase 1: u-GEMM (K=256), cols [w*256, w*256+256) ----------
    f32x4 acc1[16];
#pragma unroll
    for (int i = 0; i < 16; ++i) acc1[i] = (f32x4){0.f, 0.f, 0.f, 0.f};
    const __hip_bfloat16* Bp1 = w1b + (size_t)(w * 256 + l16) * 256 + quad * 8;
#pragma unroll
    for (int k0 = 0; k0 < 256; k0 += 32) {
        bf16x8 a = *(const bf16x8*)&x1bs[l16][quad * 8 + k0];
#pragma unroll
        for (int nt = 0; nt < 16; ++nt) {
            bf16x8 b = *(const bf16x8*)(Bp1 + (size_t)nt * 16 * 256 + k0);
            acc1[nt] = MFMA16(a, b, acc1[nt]);
        }
    }
#pragma unroll
    for (int nt = 0; nt < 16; ++nt) {
        int col = w * 256 + nt * 16 + l16;
        float bb = b1[col];
#pragma unroll
        for (int r = 0; r < 4; ++r) {
            int row = quad * 4 + r;
            us[row][col] = __float2bfloat16(fmaxf(acc1[nt][r] + bb, 0.f));
        }
    }
    __syncthreads();

    // ---------- phase 2: f-GEMM (K=1024) + residual + LN2 + mask ----------
    f32x4 acc2[4];
#pragma unroll
    for (int i = 0; i < 4; ++i) acc2[i] = (f32x4){0.f, 0.f, 0.f, 0.f};
    const __hip_bfloat16* Bp2 = w2b + (size_t)(w * 64 + l16) * 1024 + quad * 8;
    for (int k0 = 0; k0 < 1024; k0 += 32) {
        bf16x8 a = *(const bf16x8*)&us[l16][quad * 8 + k0];
#pragma unroll
        for (int nt = 0; nt < 4; ++nt) {
            bf16x8 b = *(const bf16x8*)(Bp2 + (size_t)nt * 16 * 1024 + k0);
            acc2[nt] = MFMA16(a, b, acc2[nt]);
        }
    }
    float v2[4][4];
    {
        float sum[4] = {0, 0, 0, 0}, sq[4] = {0, 0, 0, 0};
#pragma unroll
        for (int nt = 0; nt < 4; ++nt) {
            int col = w * 64 + nt * 16 + l16;
            float bb = b2[col];
#pragma unroll
            for (int r = 0; r < 4; ++r) {
                int row = quad * 4 + r;
                float x = acc2[nt][r] + bb + x1s[row][col];
                v2[nt][r] = x; sum[r] += x; sq[r] += x * x;
            }
        }
#pragma unroll
        for (int r = 0; r < 4; ++r) {
            float s_ = sum[r], q_ = sq[r];
            s_ += __shfl_xor(s_, 1);  q_ += __shfl_xor(q_, 1);
            s_ += __shfl_xor(s_, 2);  q_ += __shfl_xor(q_, 2);
            s_ += __shfl_xor(s_, 4);  q_ += __shfl_xor(q_, 4);
            s_ += __shfl_xor(s_, 8);  q_ += __shfl_xor(q_, 8);
            if (l16 == 0) { redS[w][quad * 4 + r] = s_; redQ[w][quad * 4 + r] = q_; }
        }
    }
    __syncthreads();
    {
#pragma unroll
        for (int r = 0; r < 4; ++r) {
            int row = quad * 4 + r;
            float s_ = redS[0][row] + redS[1][row] + redS[2][row] + redS[3][row];
            float q_ = redQ[0][row] + redQ[1][row] + redQ[2][row] + redQ[3][row];
            float mu = s_ * (1.f / 256);
            float var = q_ * (1.f / 256) - mu * mu;
            float rs = rsqrtf(fmaxf(var, 0.f) + 1e-5f);
            int gr = m0 + row;
            float mask = (cnt[gr] > 0) ? 1.f : 0.f;
#pragma unroll
            for (int nt = 0; nt < 4; ++nt) {
                int col = w * 64 + nt * 16 + l16;
                float y = ((v2[nt][r] - mu) * rs * g2[col] + be2[col]) * mask;
                outp[(size_t)gr * 256 + col] = y;
            }
        }
    }
}

extern "C" void kernel_launch(void* const* d_in, const int* in_sizes, int n_in,
                              void* d_out, int out_size, void* d_ws, size_t ws_size,
                              hipStream_t stream) {
    const float* h     = (const float*)d_in[0];
    const int*   batch = (const int*)d_in[1];
    const float* seed  = (const float*)d_in[3];
    const float* ipw   = (const float*)d_in[4];
    const float* ipb   = (const float*)d_in[5];
    const float* out_w = (const float*)d_in[6];
    const float* out_b = (const float*)d_in[7];
    const float* w1    = (const float*)d_in[8];
    const float* b1    = (const float*)d_in[9];
    const float* w2    = (const float*)d_in[10];
    const float* b2    = (const float*)d_in[11];
    const float* g1    = (const float*)d_in[12];
    const float* be1   = (const float*)d_in[13];
    const float* g2    = (const float*)d_in[14];
    const float* be2   = (const float*)d_in[15];

    int N = in_sizes[1];            // 400000 nodes
    int G = out_size / DIM;         // 4096 graphs

    float* ws = (float*)d_ws;
    float* cvec     = ws + OFF_C;
    float* dconst   = ws + OFF_D;
    float* constvec = ws + OFF_CONST;
    __hip_bfloat16* P2b = (__hip_bfloat16*)(ws + OFF_P2B);
    __hip_bfloat16* w1b = (__hip_bfloat16*)(ws + OFF_W1B);
    __hip_bfloat16* w2b = (__hip_bfloat16*)(ws + OFF_W2B);
    __hip_bfloat16* Tb  = (__hip_bfloat16*)(ws + OFF_TB);
    int*   cnt      = (int*)(ws + OFF_CNT);
    int*   startsp  = (int*)(ws + OFF_STARTS);

    int sblocks = (N + 255) / 256;
    prep_all_kernel<<<1281 + sblocks, 256, 0, stream>>>(
        seed, ipw, ipb, out_w, out_b, w1, w2, batch,
        cvec, dconst, constvec, P2b, w1b, w2b, startsp, N, G);
    attn_pool_kernel<<<G, 256, 0, stream>>>(h, startsp, cvec, dconst, Tb, cnt);
    mlp_fused_kernel<<<G / 16, 256, 0, stream>>>(Tb, P2b, constvec, seed, g1, be1,
                                                 w1b, b1, w2b, b2, g2, be2, cnt,
                                                 (float*)d_out);
}

// Round 4
// 663.727 us; speedup vs baseline: 1.2187x; 1.0171x over previous
//
#include <hip/hip_runtime.h>
#include <hip/hip_bf16.h>

// PMA pooling block:
//  scores[n,h] = h[n]·c[h] + d[h]        (c,d precomputed from seed,Wq,Wk)
//  T[g,h*256+d] = segment softmax-weighted mean of h rows (unstabilized exp:
//                 |score| <~ 3 for this data, ratios identical to reference)
//  o  = Tb @ P2b^T + const   (P2 = out_w ∘ Wv folded, bf16 [256,1024], MFMA)
//  x1 = LN(o+seed); u = relu(x1@w1^T+b1); f = u@w2^T+b2; out = LN(x1+f)·mask
//  -> o/u/f + both LNs fused into ONE kernel (LDS-resident intermediates)
// attn_pool v4: wave-independent chunks. Each wave owns rows j==wave (mod 4)
// end-to-end: score -> in-wave shfl broadcast of exp -> weighted sum over all
// 256 cols (4 col-groups/lane). No cross-wave esc exchange => ONE
// __syncthreads per chunk, whose implicit vmcnt(0) is exactly the wait for
// the prefetch issued after the PREVIOUS barrier (full-phase overlap, no
// mid-chunk drain, no raw-asm barriers). Per-wave partials merged once per
// graph in a 16KB scratch overlaid on hbuf. CHUNK=16 -> 32.3KB LDS, 4 blk/CU.

#define DIM 256
#define CHUNK 16

typedef short bf16x8 __attribute__((ext_vector_type(8)));  // 8 bf16 = 4 VGPRs
typedef float f32x4  __attribute__((ext_vector_type(4)));
#define MFMA16(a, b, c) __builtin_amdgcn_mfma_f32_16x16x32_bf16(a, b, c, 0, 0, 0)

// async global->LDS, 16B per lane; LDS dest = wave-uniform base + lane*16
#define GLOAD_LDS16(gp, lp)                                          \
    __builtin_amdgcn_global_load_lds(                                \
        (const __attribute__((address_space(1))) void*)(gp),         \
        (__attribute__((address_space(3))) void*)(lp), 16, 0, 0)

// ---- workspace layout (float offsets; all bf16 arrays 16B-aligned) ----
#define OFF_C      0          // c[4][256] fp32
#define OFF_D      1024       // dconst[4]
#define OFF_CONST  1040       // constvec[256]
#define OFF_P2B    2048       // P2 bf16 [256][1024]
#define OFF_W1B    133120     // w1 bf16 [1024][256]
#define OFF_W2B    264192     // w2 bf16 [256][1024]
#define OFF_TB     395264     // T  bf16 [4096][1024]
#define OFF_CNT    6162432    // cnt int [4096]
#define OFF_STARTS 6166528    // starts int [4097]

// ================= prep: c/dconst/constvec + P2b + w1b/w2b + starts =====
// blocks 0..1023: P2b; 1024: prep1; 1025..1152: w1b; 1153..1280: w2b;
// 1281+: segment starts scatter (sorted batch -> unique writer per graph)
__global__ __launch_bounds__(256) void prep_all_kernel(
    const float* __restrict__ seed, const float* __restrict__ ipw,
    const float* __restrict__ ipb, const float* __restrict__ out_w,
    const float* __restrict__ out_b, const float* __restrict__ w1,
    const float* __restrict__ w2, const int* __restrict__ batch,
    float* __restrict__ cvec, float* __restrict__ dconst,
    float* __restrict__ constvec, __hip_bfloat16* __restrict__ P2b,
    __hip_bfloat16* __restrict__ w1b, __hip_bfloat16* __restrict__ w2b,
    int* __restrict__ starts, int N, int G)
{
    int b = blockIdx.x, t = threadIdx.x;
    __shared__ float q_s[DIM];
    if (b < 1024) {
        // P2[i][hD*256+t] = sum_j out_w[i,hD*64+j]*Wv[hD*64+j][t]
        int i = b >> 2, hD = b & 3;
        float a = 0.f;
        for (int j = 0; j < 64; ++j)
            a += out_w[i * DIM + hD * 64 + j]
               * ipw[(size_t)(2 * DIM + hD * 64 + j) * DIM + t];
        P2b[(size_t)i * 1024 + hD * DIM + t] = __float2bfloat16(a);
    } else if (b == 1024) {
        const float scale = 0.125f; // 1/sqrt(64)
        float acc = ipb[t];
        for (int d = 0; d < DIM; ++d) acc += seed[d] * ipw[t * DIM + d];
        q_s[t] = acc;
        __syncthreads();
        for (int hh = 0; hh < 4; ++hh) {
            float a = 0.f;
            for (int j = 0; j < 64; ++j)
                a += q_s[hh * 64 + j] * ipw[(size_t)(DIM + hh * 64 + j) * DIM + t];
            cvec[hh * DIM + t] = a * scale;
        }
        if (t < 4) {
            float a = 0.f;
            for (int j = 0; j < 64; ++j)
                a += q_s[t * 64 + j] * ipb[DIM + t * 64 + j];
            dconst[t] = a * scale;
        }
        float cc = out_b[t];
        for (int c = 0; c < DIM; ++c)
            cc += out_w[t * DIM + c] * ipb[2 * DIM + c];
        constvec[t] = cc;
    } else if (b < 1153) {
        int base = (b - 1025) * 2048 + t;
        for (int i = 0; i < 8; ++i)
            w1b[base + i * 256] = __float2bfloat16(w1[base + i * 256]);
    } else if (b < 1281) {
        int base = (b - 1153) * 2048 + t;
        for (int i = 0; i < 8; ++i)
            w2b[base + i * 256] = __float2bfloat16(w2[base + i * 256]);
    } else {
        int n = (b - 1281) * 256 + t;
        if (n < N) {
            int bn = batch[n];
            int bp = (n == 0) ? -1 : batch[n - 1];
            for (int gg = bp + 1; gg <= bn; ++gg) starts[gg] = n;
            if (n == N - 1)
                for (int gg = bn + 1; gg <= G; ++gg) starts[gg] = N;
        }
    }
}

// ================= attn pooling: per-graph exp-weighted mean ============
__global__ __launch_bounds__(256) void attn_pool_kernel(
    const float* __restrict__ hmat, const int* __restrict__ starts,
    const float* __restrict__ cvec, const float* __restrict__ dconst,
    __hip_bfloat16* __restrict__ Tb, int* __restrict__ cnt)
{
    int g = blockIdx.x;
    int tid = threadIdx.x;
    int lane = tid & 63, wave = tid >> 6;

    __shared__ float hbuf[2][CHUNK][DIM];  // 32 KB linear (gload_lds dest);
                                           // reused as partial-sum scratch
    __shared__ float lred[4][4];           // [wave][head] partial denominators

    int s = starts[g], e = starts[g + 1];
    if (tid == 0) cnt[g] = e - s;
    size_t tbase = (size_t)g * 1024;
    if (e == s) {
        __hip_bfloat16 z = __float2bfloat16(0.f);
        Tb[tbase + tid] = z; Tb[tbase + 256 + tid] = z;
        Tb[tbase + 512 + tid] = z; Tb[tbase + 768 + tid] = z;
        return;
    }

    int hh = lane & 3, seg = lane >> 2;
    const float* cb = cvec + hh * DIM + seg * 16;
    float4 cr0 = *(const float4*)(cb + 0);
    float4 cr1 = *(const float4*)(cb + 4);
    float4 cr2 = *(const float4*)(cb + 8);
    float4 cr3 = *(const float4*)(cb + 12);
    float dc_mine = dconst[hh];

    // per-wave partial sums: S[head][colgroup], col = cg*64 + lane
    float S00 = 0.f, S01 = 0.f, S02 = 0.f, S03 = 0.f;
    float S10 = 0.f, S11 = 0.f, S12 = 0.f, S13 = 0.f;
    float S20 = 0.f, S21 = 0.f, S22 = 0.f, S23 = 0.f;
    float S30 = 0.f, S31 = 0.f, S32 = 0.f, S33 = 0.f;
    float lp = 0.f;  // denominator partial for head hh (dup across seg groups)

    // stage chunk 0 into buf 0 (4 rows per wave, 1 KB per call)
    {
        int c0 = min(CHUNK, e - s);
#pragma unroll
        for (int i = 0; i < 4; ++i) {
            int r = wave * 4 + i;
            if (r < c0)
                GLOAD_LDS16(&hmat[(size_t)(s + r) * DIM + lane * 4],
                            &hbuf[0][r][0]);
        }
    }

    int cur = 0;
    for (int n0 = s; n0 < e; n0 += CHUNK, cur ^= 1) {
        int ccnt = min(CHUNK, e - n0);
        // implicit vmcnt(0): exactly the wait for chunk-cur's staging;
        // also: buf[cur^1]'s previous readers are all past this point.
        __syncthreads();

        int n1 = n0 + CHUNK;
        if (n1 < e) {      // prefetch next chunk; in flight until NEXT barrier
            int cn = min(CHUNK, e - n1);
#pragma unroll
            for (int i = 0; i < 4; ++i) {
                int r = wave * 4 + i;
                if (r < cn)
                    GLOAD_LDS16(&hmat[(size_t)(n1 + r) * DIM + lane * 4],
                                &hbuf[cur ^ 1][r][0]);
            }
        }

        // own rows end-to-end: score -> broadcast exp -> weighted sum
        for (int j = wave; j < ccnt; j += 4) {
            const float* hb = &hbuf[cur][j][0];
            const float* hs = hb + seg * 16;
            float4 h0 = *(const float4*)(hs + 0);
            float4 h1 = *(const float4*)(hs + 4);
            float4 h2 = *(const float4*)(hs + 8);
            float4 h3 = *(const float4*)(hs + 12);
            float p = h0.x * cr0.x + h0.y * cr0.y + h0.z * cr0.z + h0.w * cr0.w
                    + h1.x * cr1.x + h1.y * cr1.y + h1.z * cr1.z + h1.w * cr1.w
                    + h2.x * cr2.x + h2.y * cr2.y + h2.z * cr2.z + h2.w * cr2.w
                    + h3.x * cr3.x + h3.y * cr3.y + h3.z * cr3.z + h3.w * cr3.w;
            p += __shfl_xor(p, 4);
            p += __shfl_xor(p, 8);
            p += __shfl_xor(p, 16);
            p += __shfl_xor(p, 32);   // full dot for head hh on every lane
            float ev = __expf(p + dc_mine);   // |score| small: unstabilized OK
            lp += ev;
            float e0 = __shfl(ev, 0), e1 = __shfl(ev, 1);
            float e2 = __shfl(ev, 2), e3 = __shfl(ev, 3);
            float v0 = hb[lane], v1 = hb[64 + lane];
            float v2 = hb[128 + lane], v3 = hb[192 + lane];
            S00 = fmaf(e0, v0, S00); S01 = fmaf(e0, v1, S01);
            S02 = fmaf(e0, v2, S02); S03 = fmaf(e0, v3, S03);
            S10 = fmaf(e1, v0, S10); S11 = fmaf(e1, v1, S11);
            S12 = fmaf(e1, v2, S12); S13 = fmaf(e1, v3, S13);
            S20 = fmaf(e2, v0, S20); S21 = fmaf(e2, v1, S21);
            S22 = fmaf(e2, v2, S22); S23 = fmaf(e2, v3, S23);
            S30 = fmaf(e3, v0, S30); S31 = fmaf(e3, v1, S31);
            S32 = fmaf(e3, v2, S32); S33 = fmaf(e3, v3, S33);
        }
        // no tail barrier: next head barrier is the WAR fence
    }

    // ---- merge the 4 per-wave partials (scratch overlaid on hbuf) ----
    __syncthreads();                       // all waves done with hbuf
    float* part = &hbuf[0][0][0];          // [wave][head][cg][lane] = 16 KB
#define PIDX(w_, h_, c_) ((((w_) * 4 + (h_)) * 4 + (c_)) * 64 + lane)
    part[PIDX(wave, 0, 0)] = S00; part[PIDX(wave, 0, 1)] = S01;
    part[PIDX(wave, 0, 2)] = S02; part[PIDX(wave, 0, 3)] = S03;
    part[PIDX(wave, 1, 0)] = S10; part[PIDX(wave, 1, 1)] = S11;
    part[PIDX(wave, 1, 2)] = S12; part[PIDX(wave, 1, 3)] = S13;
    part[PIDX(wave, 2, 0)] = S20; part[PIDX(wave, 2, 1)] = S21;
    part[PIDX(wave, 2, 2)] = S22; part[PIDX(wave, 2, 3)] = S23;
    part[PIDX(wave, 3, 0)] = S30; part[PIDX(wave, 3, 1)] = S31;
    part[PIDX(wave, 3, 2)] = S32; part[PIDX(wave, 3, 3)] = S33;
#undef PIDX
    if (lane < 4) lred[wave][lane] = lp;
    __syncthreads();

    int cg = tid >> 6, ln = tid & 63;      // output col = tid = cg*64+ln
#pragma unroll
    for (int h = 0; h < 4; ++h) {
        int base = (h * 4 + cg) * 64 + ln;
        float sum = part[base] + part[base + 1024]
                  + part[base + 2048] + part[base + 3072];
        float den = lred[0][h] + lred[1][h] + lred[2][h] + lred[3][h];
        Tb[tbase + h * 256 + tid] = __float2bfloat16(sum / den);
    }
}

// === fused: o = Tb@P2b^T+const; x1 = LN1(o+seed); u = relu(x1@w1^T+b1);
//            f = u@w2^T+b2; out = LN2(x1+f)*mask — all intermediates in LDS.
// 256 threads = 4 waves; each wave owns a 64-col (o/f) or 256-col (u) slice.
__global__ __launch_bounds__(256) void mlp_fused_kernel(
    const __hip_bfloat16* __restrict__ Tb, const __hip_bfloat16* __restrict__ P2b,
    const float* __restrict__ constvec, const float* __restrict__ seed,
    const float* __restrict__ g1, const float* __restrict__ be1,
    const __hip_bfloat16* __restrict__ w1b, const float* __restrict__ b1,
    const __hip_bfloat16* __restrict__ w2b, const float* __restrict__ b2,
    const float* __restrict__ g2, const float* __restrict__ be2,
    const int* __restrict__ cnt, float* __restrict__ outp)
{
    int m0 = blockIdx.x * 16;
    int tid = threadIdx.x;
    int w = tid >> 6, lane = tid & 63, quad = lane >> 4, l16 = lane & 15;

    __shared__ float x1s[16][260];               // 16.6 KB  (x1 fp32, residual)
    __shared__ __hip_bfloat16 x1bs[16][264];     //  8.25 KB (x1 bf16, GEMM A)
    __shared__ __hip_bfloat16 us[16][1032];      // 33 KB    (u bf16, GEMM A)
    __shared__ float redS[4][16], redQ[4][16];   // cross-wave LN partials

    // ---------- phase 0: o-GEMM (K=1024), cols [w*64, w*64+64) ----------
    f32x4 acc0[4];
#pragma unroll
    for (int i = 0; i < 4; ++i) acc0[i] = (f32x4){0.f, 0.f, 0.f, 0.f};
    const __hip_bfloat16* Ap0 = Tb + (size_t)(m0 + l16) * 1024 + quad * 8;
    const __hip_bfloat16* Bp0 = P2b + (size_t)(w * 64 + l16) * 1024 + quad * 8;
    for (int k0 = 0; k0 < 1024; k0 += 32) {
        bf16x8 a = *(const bf16x8*)(Ap0 + k0);
#pragma unroll
        for (int nt = 0; nt < 4; ++nt) {
            bf16x8 b = *(const bf16x8*)(Bp0 + (size_t)nt * 16 * 1024 + k0);
            acc0[nt] = MFMA16(a, b, acc0[nt]);
        }
    }
    // epilogue: +const+seed, LN1 partials (this wave covers 64 of 256 cols)
    float v0[4][4];
    {
        float sum[4] = {0, 0, 0, 0}, sq[4] = {0, 0, 0, 0};
#pragma unroll
        for (int nt = 0; nt < 4; ++nt) {
            int col = w * 64 + nt * 16 + l16;
            float cv = constvec[col] + seed[col];
#pragma unroll
            for (int r = 0; r < 4; ++r) {
                float x = acc0[nt][r] + cv;
                v0[nt][r] = x; sum[r] += x; sq[r] += x * x;
            }
        }
#pragma unroll
        for (int r = 0; r < 4; ++r) {
            float s_ = sum[r], q_ = sq[r];
            s_ += __shfl_xor(s_, 1);  q_ += __shfl_xor(q_, 1);
            s_ += __shfl_xor(s_, 2);  q_ += __shfl_xor(q_, 2);
            s_ += __shfl_xor(s_, 4);  q_ += __shfl_xor(q_, 4);
            s_ += __shfl_xor(s_, 8);  q_ += __shfl_xor(q_, 8);
            if (l16 == 0) { redS[w][quad * 4 + r] = s_; redQ[w][quad * 4 + r] = q_; }
        }
    }
    __syncthreads();
    {
        float mu_r[4], rs_r[4];
#pragma unroll
        for (int r = 0; r < 4; ++r) {
            int row = quad * 4 + r;
            float s_ = redS[0][row] + redS[1][row] + redS[2][row] + redS[3][row];
            float q_ = redQ[0][row] + redQ[1][row] + redQ[2][row] + redQ[3][row];
            float mu = s_ * (1.f / 256);
            float var = q_ * (1.f / 256) - mu * mu;
            mu_r[r] = mu;
            rs_r[r] = rsqrtf(fmaxf(var, 0.f) + 1e-5f);
        }
#pragma unroll
        for (int nt = 0; nt < 4; ++nt) {
            int col = w * 64 + nt * 16 + l16;
            float gg = g1[col], bb = be1[col];
#pragma unroll
            for (int r = 0; r < 4; ++r) {
                int row = quad * 4 + r;
                float y = (v0[nt][r] - mu_r[r]) * rs_r[r] * gg + bb;
                x1s[row][col] = y;
                x1bs[row][col] = __float2bfloat16(y);
            }
        }
    }
    __syncthreads();

    // ---------- phase 1: u-GEMM (K=256), cols [w*256, w*256+256) ----------
    f32x4 acc1[16];
#pragma unroll
    for (int i = 0; i < 16; ++i) acc1[i] = (f32x4){0.f, 0.f, 0.f, 0.f};
    const __hip_bfloat16* Bp1 = w1b + (size_t)(w * 256 + l16) * 256 + quad * 8;
#pragma unroll
    for (int k0 = 0; k0 < 256; k0 += 32) {
        bf16x8 a = *(const bf16x8*)&x1bs[l16][quad * 8 + k0];
#pragma unroll
        for (int nt = 0; nt < 16; ++nt) {
            bf16x8 b = *(const bf16x8*)(Bp1 + (size_t)nt * 16 * 256 + k0);
            acc1[nt] = MFMA16(a, b, acc1[nt]);
        }
    }
#pragma unroll
    for (int nt = 0; nt < 16; ++nt) {
        int col = w * 256 + nt * 16 + l16;
        float bb = b1[col];
#pragma unroll
        for (int r = 0; r < 4; ++r) {
            int row = quad * 4 + r;
            us[row][col] = __float2bfloat16(fmaxf(acc1[nt][r] + bb, 0.f));
        }
    }
    __syncthreads();

    // ---------- phase 2: f-GEMM (K=1024) + residual + LN2 + mask ----------
    f32x4 acc2[4];
#pragma unroll
    for (int i = 0; i < 4; ++i) acc2[i] = (f32x4){0.f, 0.f, 0.f, 0.f};
    const __hip_bfloat16* Bp2 = w2b + (size_t)(w * 64 + l16) * 1024 + quad * 8;
    for (int k0 = 0; k0 < 1024; k0 += 32) {
        bf16x8 a = *(const bf16x8*)&us[l16][quad * 8 + k0];
#pragma unroll
        for (int nt = 0; nt < 4; ++nt) {
            bf16x8 b = *(const bf16x8*)(Bp2 + (size_t)nt * 16 * 1024 + k0);
            acc2[nt] = MFMA16(a, b, acc2[nt]);
        }
    }
    float v2[4][4];
    {
        float sum[4] = {0, 0, 0, 0}, sq[4] = {0, 0, 0, 0};
#pragma unroll
        for (int nt = 0; nt < 4; ++nt) {
            int col = w * 64 + nt * 16 + l16;
            float bb = b2[col];
#pragma unroll
            for (int r = 0; r < 4; ++r) {
                int row = quad * 4 + r;
                float x = acc2[nt][r] + bb + x1s[row][col];
                v2[nt][r] = x; sum[r] += x; sq[r] += x * x;
            }
        }
#pragma unroll
        for (int r = 0; r < 4; ++r) {
            float s_ = sum[r], q_ = sq[r];
            s_ += __shfl_xor(s_, 1);  q_ += __shfl_xor(q_, 1);
            s_ += __shfl_xor(s_, 2);  q_ += __shfl_xor(q_, 2);
            s_ += __shfl_xor(s_, 4);  q_ += __shfl_xor(q_, 4);
            s_ += __shfl_xor(s_, 8);  q_ += __shfl_xor(q_, 8);
            if (l16 == 0) { redS[w][quad * 4 + r] = s_; redQ[w][quad * 4 + r] = q_; }
        }
    }
    __syncthreads();
    {
#pragma unroll
        for (int r = 0; r < 4; ++r) {
            int row = quad * 4 + r;
            float s_ = redS[0][row] + redS[1][row] + redS[2][row] + redS[3][row];
            float q_ = redQ[0][row] + redQ[1][row] + redQ[2][row] + redQ[3][row];
            float mu = s_ * (1.f / 256);
            float var = q_ * (1.f / 256) - mu * mu;
            float rs = rsqrtf(fmaxf(var, 0.f) + 1e-5f);
            int gr = m0 + row;
            float mask = (cnt[gr] > 0) ? 1.f : 0.f;
#pragma unroll
            for (int nt = 0; nt < 4; ++nt) {
                int col = w * 64 + nt * 16 + l16;
                float y = ((v2[nt][r] - mu) * rs * g2[col] + be2[col]) * mask;
                outp[(size_t)gr * 256 + col] = y;
            }
        }
    }
}

extern "C" void kernel_launch(void* const* d_in, const int* in_sizes, int n_in,
                              void* d_out, int out_size, void* d_ws, size_t ws_size,
                              hipStream_t stream) {
    const float* h     = (const float*)d_in[0];
    const int*   batch = (const int*)d_in[1];
    const float* seed  = (const float*)d_in[3];
    const float* ipw   = (const float*)d_in[4];
    const float* ipb   = (const float*)d_in[5];
    const float* out_w = (const float*)d_in[6];
    const float* out_b = (const float*)d_in[7];
    const float* w1    = (const float*)d_in[8];
    const float* b1    = (const float*)d_in[9];
    const float* w2    = (const float*)d_in[10];
    const float* b2    = (const float*)d_in[11];
    const float* g1    = (const float*)d_in[12];
    const float* be1   = (const float*)d_in[13];
    const float* g2    = (const float*)d_in[14];
    const float* be2   = (const float*)d_in[15];

    int N = in_sizes[1];            // 400000 nodes
    int G = out_size / DIM;         // 4096 graphs

    float* ws = (float*)d_ws;
    float* cvec     = ws + OFF_C;
    float* dconst   = ws + OFF_D;
    float* constvec = ws + OFF_CONST;
    __hip_bfloat16* P2b = (__hip_bfloat16*)(ws + OFF_P2B);
    __hip_bfloat16* w1b = (__hip_bfloat16*)(ws + OFF_W1B);
    __hip_bfloat16* w2b = (__hip_bfloat16*)(ws + OFF_W2B);
    __hip_bfloat16* Tb  = (__hip_bfloat16*)(ws + OFF_TB);
    int*   cnt      = (int*)(ws + OFF_CNT);
    int*   startsp  = (int*)(ws + OFF_STARTS);

    int sblocks = (N + 255) / 256;
    prep_all_kernel<<<1281 + sblocks, 256, 0, stream>>>(
        seed, ipw, ipb, out_w, out_b, w1, w2, batch,
        cvec, dconst, constvec, P2b, w1b, w2b, startsp, N, G);
    attn_pool_kernel<<<G, 256, 0, stream>>>(h, startsp, cvec, dconst, Tb, cnt);
    mlp_fused_kernel<<<G / 16, 256, 0, stream>>>(Tb, P2b, constvec, seed, g1, be1,
                                                 w1b, b1, w2b, b2, g2, be2, cnt,
                                                 (float*)d_out);
}